// Round 5
// baseline (232.611 us; speedup 1.0000x reference)
//
#include <hip/hip_runtime.h>
#include <stdint.h>

// Problem constants (B, C=1, H, W) from the reference.
#define H_ 1024
#define W_ 1024
#define B_ 16
#define TH 8                   // output rows per block (STEPS=14 fully unrolls; 22 did NOT - r3 spill disaster)
#define STEPS (TH + 6)         // input rows streamed (halo 3 each side)
#define GX (H_ / TH)           // 128 blocks in y-dim of image
#define NBLK (GX * B_)         // 2048 blocks
#define NACC 13
// partials layout (SoA): partials[j * NBLK + bid]
//  j: 0=sum_pred, then k=3,5,7: {1,5,9}=sum_dil {2,6,10}=sum_p*dil
//                               {3,7,11}=sum_ero {4,8,12}=sum_p*ero

// async global->LDS, 16B per lane; lds dest must be wave-uniform base (+lane*16 implicit)
__device__ __forceinline__ void gl2lds16(const float* g, float* l) {
  __builtin_amdgcn_global_load_lds(
      (const __attribute__((address_space(1))) void*)g,
      (__attribute__((address_space(3))) void*)l,
      16, 0, 0);
}

// Joint dilation+erosion sliding-row gather stencil (r2 algebra, verified):
// horizontal windows h0/h3/h5/h7 built once per input row, pushed into register
// ring queues (constant indices after full unroll); output row y = t-3:
//   k3 = op(h3[y], h0[y-1], h0[y+1])
//   k5 = op(h5[y], h3[y-1], h3[y+1], h0[y-2], h0[y+2])
//   k7 = op(h7[y], h5[y-1], h5[y+1], h5[y-2], h5[y+2], h0[y-3], h0[y+3])
// Geodesic (exclude-OOB) border == clamped-index border (clamped taps duplicate
// values lying in a superset part of the window) -> exact.
// Memory path: teacher + pred rows staged into LDS double-buffers via
// global_load_lds issued one step ahead; __syncthreads' vmcnt(0) drain pins the
// pipeline (compiler can't sink the stage to its use).
__global__ __launch_bounds__(256, 2) void k_partials(const float* __restrict__ pred,
                                                     const float* __restrict__ tch,
                                                     float* __restrict__ partials) {
  __shared__ float tbuf[2][1032];   // [4..1027] = cols 0..1023; [0..3],[1028..1031] unused pads
  __shared__ float qbuf[2][1024];   // pred rows
  __shared__ float red[4][NACC];

  const int tid = threadIdx.x;
  const int b   = blockIdx.y;
  const int y0  = blockIdx.x * TH;
  const int x0  = tid * 4;
  const int wv  = tid >> 6;
  const float* tb = tch  + (size_t)b * (H_ * W_);
  const float* pb = pred + (size_t)b * (H_ * W_);

  float acc[NACC];
#pragma unroll
  for (int j = 0; j < NACC; j++) acc[j] = 0.f;

  float h0q[7][4];
  float h3M[5][4], h3N[5][4];
  float h5M[6][4], h5N[6][4];
  float h7M[4][4], h7N[4][4];

  // prolog: stage teacher row for step 0
  {
    const int t = y0 - 3;
    const int trow = t < 0 ? 0 : t;
    gl2lds16(tb + (size_t)trow * W_ + x0, &tbuf[0][4 + (wv << 8)]);
  }
  __syncthreads();

#pragma unroll
  for (int s = 0; s < STEPS; ++s) {
    // issue next step's stages (drained by this step's end-of-iteration barrier)
    if (s + 1 < STEPS) {
      const int t = y0 + s + 1 - 3;
      const int trow = t < 0 ? 0 : (t >= H_ ? H_ - 1 : t);
      gl2lds16(tb + (size_t)trow * W_ + x0, &tbuf[(s + 1) & 1][4 + (wv << 8)]);
      if (s >= 5)  // emit at s+1 uses pred row y0+s-5
        gl2lds16(pb + (size_t)(y0 + s - 5) * W_ + x0, &qbuf[(s + 1) & 1][wv << 8]);
    }

    // a[0..11] = cols x0-4 .. x0+7 from LDS (3x ds_read_b128)
    const float4* t4 = reinterpret_cast<const float4*>(&tbuf[s & 1][x0]);
    const float4 A0 = t4[0], A1 = t4[1], A2 = t4[2];
    float a[12] = {A0.x, A0.y, A0.z, A0.w, A1.x, A1.y, A1.z, A1.w, A2.x, A2.y, A2.z, A2.w};
    if (tid == 0)   { a[0] = a[1] = a[2]  = a[3]  = a[4]; }   // x-clamp (exact)
    if (tid == 255) { a[8] = a[9] = a[10] = a[11] = a[7]; }

    float QM[8], QN[8];
#pragma unroll
    for (int i = 1; i <= 7; ++i) {
      QM[i] = fmaxf(fmaxf(a[i], a[i + 1]), a[i + 2]);   // v_max3
      QN[i] = fminf(fminf(a[i], a[i + 1]), a[i + 2]);   // v_min3
    }
#pragma unroll
    for (int c = 0; c < 4; ++c) {
      h0q[s % 7][c] = a[c + 4];
      h3M[s % 5][c] = QM[c + 3];
      h3N[s % 5][c] = QN[c + 3];
      h5M[s % 6][c] = fmaxf(QM[c + 2], QM[c + 4]);
      h5N[s % 6][c] = fminf(QN[c + 2], QN[c + 4]);
      h7M[s % 4][c] = fmaxf(fmaxf(QM[c + 1], QM[c + 4]), a[c + 7]);
      h7N[s % 4][c] = fminf(fminf(QN[c + 1], QN[c + 4]), a[c + 7]);
    }

    if (s >= 6) {
      const float4 pv = *reinterpret_cast<const float4*>(&qbuf[s & 1][x0]);
      const float p[4] = {pv.x, pv.y, pv.z, pv.w};
#pragma unroll
      for (int c = 0; c < 4; ++c) {
        const float d3v = fmaxf(fmaxf(h3M[(s + 2) % 5][c], h0q[(s + 3) % 7][c]), h0q[(s + 5) % 7][c]);
        const float e3v = fminf(fminf(h3N[(s + 2) % 5][c], h0q[(s + 3) % 7][c]), h0q[(s + 5) % 7][c]);

        float d5v = fmaxf(fmaxf(h5M[(s + 3) % 6][c], h3M[(s + 1) % 5][c]), h3M[(s + 3) % 5][c]);
        d5v = fmaxf(fmaxf(d5v, h0q[(s + 2) % 7][c]), h0q[(s + 6) % 7][c]);
        float e5v = fminf(fminf(h5N[(s + 3) % 6][c], h3N[(s + 1) % 5][c]), h3N[(s + 3) % 5][c]);
        e5v = fminf(fminf(e5v, h0q[(s + 2) % 7][c]), h0q[(s + 6) % 7][c]);

        float d7v = fmaxf(fmaxf(h7M[(s + 1) % 4][c], h5M[(s + 2) % 6][c]), h5M[(s + 4) % 6][c]);
        d7v = fmaxf(fmaxf(d7v, h5M[(s + 1) % 6][c]), h5M[(s + 5) % 6][c]);
        d7v = fmaxf(fmaxf(d7v, h0q[(s + 1) % 7][c]), h0q[s % 7][c]);
        float e7v = fminf(fminf(h7N[(s + 1) % 4][c], h5N[(s + 2) % 6][c]), h5N[(s + 4) % 6][c]);
        e7v = fminf(fminf(e7v, h5N[(s + 1) % 6][c]), h5N[(s + 5) % 6][c]);
        e7v = fminf(fminf(e7v, h0q[(s + 1) % 7][c]), h0q[s % 7][c]);

        acc[0]  += p[c];
        acc[1]  += d3v;  acc[2]  = fmaf(p[c], d3v, acc[2]);
        acc[3]  += e3v;  acc[4]  = fmaf(p[c], e3v, acc[4]);
        acc[5]  += d5v;  acc[6]  = fmaf(p[c], d5v, acc[6]);
        acc[7]  += e5v;  acc[8]  = fmaf(p[c], e5v, acc[8]);
        acc[9]  += d7v;  acc[10] = fmaf(p[c], d7v, acc[10]);
        acc[11] += e7v;  acc[12] = fmaf(p[c], e7v, acc[12]);
      }
    }

    __syncthreads();  // drains the stages issued this iteration; protects buffer reuse
  }

  // wave (64-lane) shuffle reduction, then cross-wave via LDS
#pragma unroll
  for (int j = 0; j < NACC; j++) {
    float v = acc[j];
#pragma unroll
    for (int off = 32; off > 0; off >>= 1) v += __shfl_down(v, off, 64);
    acc[j] = v;
  }
  const int lane = tid & 63;
  if (lane == 0) {
#pragma unroll
    for (int j = 0; j < NACC; j++) red[wv][j] = acc[j];
  }
  __syncthreads();
  if (tid == 0) {
    const int bid = blockIdx.y * gridDim.x + blockIdx.x;
#pragma unroll
    for (int j = 0; j < NACC; j++)
      partials[j * NBLK + bid] = red[0][j] + red[1][j] + red[2][j] + red[3][j];
  }
}

__global__ __launch_bounds__(256) void k_final(const float* __restrict__ partials,
                                               float* __restrict__ out) {
  const int tid = threadIdx.x;
  double acc[NACC];
#pragma unroll
  for (int j = 0; j < NACC; j++) acc[j] = 0.0;
#pragma unroll
  for (int k = 0; k < NBLK / 256; k++) {
#pragma unroll
    for (int j = 0; j < NACC; j++)
      acc[j] += (double)partials[j * NBLK + tid + k * 256];   // coalesced, independent
  }
#pragma unroll
  for (int j = 0; j < NACC; j++) {
#pragma unroll
    for (int off = 32; off > 0; off >>= 1) acc[j] += __shfl_down(acc[j], off, 64);
  }
  __shared__ double red[4][NACC];
  const int lane = tid & 63, wv = tid >> 6;
  if (lane == 0) {
#pragma unroll
    for (int j = 0; j < NACC; j++) red[wv][j] = acc[j];
  }
  __syncthreads();
  if (tid == 0) {
    double t_[NACC];
#pragma unroll
    for (int j = 0; j < NACC; j++) t_[j] = red[0][j] + red[1][j] + red[2][j] + red[3][j];
    const double Sp = t_[0];
    double total = 0.0;
#pragma unroll
    for (int k = 0; k < 3; k++) {
      const double Sd = t_[1 + 4 * k], Id = t_[2 + 4 * k];
      const double Se = t_[3 + 4 * k], Ie = t_[4 + 4 * k];
      double cd = Sp + Sd; if (cd < 1e-7) cd = 1e-7;
      double ce = Sp + Se; if (ce < 1e-7) ce = 1e-7;
      total += (1.0 - 2.0 * Id / cd) * (Sd > 0.0 ? 1.0 : 0.0);
      total += (1.0 - 2.0 * Ie / ce) * (Se > 0.0 ? 1.0 : 0.0);
    }
    out[0] = (float)(total / 3.0);
  }
}

extern "C" void kernel_launch(void* const* d_in, const int* in_sizes, int n_in,
                              void* d_out, int out_size, void* d_ws, size_t ws_size,
                              hipStream_t stream) {
  const float* pred = (const float*)d_in[0];  // pred_student_prob
  const float* tch  = (const float*)d_in[1];  // teacher_prob
  float* partials = (float*)d_ws;             // NACC * NBLK floats; fully written each launch

  k_partials<<<dim3(GX, B_), 256, 0, stream>>>(pred, tch, partials);
  k_final<<<1, 256, 0, stream>>>(partials, (float*)d_out);
}

// Round 6
// 179.372 us; speedup vs baseline: 1.2968x; 1.2968x over previous
//
#include <hip/hip_runtime.h>

// Problem constants (B, C=1, H, W) from the reference.
#define H_ 1024
#define W_ 1024
#define B_ 16
#define TH 8                   // output rows per block (STEPS=14 fully unrolls; 22 spilled - r3)
#define STEPS (TH + 6)         // input rows streamed (halo 3 each side)
#define GX (H_ / TH)           // 128 y-tiles per image
#define NACC 13
#define ACC_STRIDE 16          // pad accumulators to separate 64B cache lines (atomic parallelism)

// d_ws layout: float accum[NACC * ACC_STRIDE]; zeroed via hipMemsetAsync each launch.
//  j: 0=sum_pred, then k=3,5,7: {1,5,9}=sum_dil {2,6,10}=sum_p*dil
//                               {3,7,11}=sum_ero {4,8,12}=sum_p*ero

// Joint dilation+erosion sliding-row gather stencil (r2 body, verified @59us):
// horizontal windows h0/h3/h5/h7 built once per input row, pushed into register
// ring queues (constant indices after full unroll); output row y = t-3:
//   k3 = op(h3[y], h0[y-1], h0[y+1])
//   k5 = op(h5[y], h3[y-1], h3[y+1], h0[y-2], h0[y+2])
//   k7 = op(h7[y], h5[y-1], h5[y+1], h5[y-2], h5[y+2], h0[y-3], h0[y+3])
// Geodesic (exclude-OOB) border == clamped-index border (clamped taps duplicate
// values lying in a superset part of the window) -> exact.
__global__ __launch_bounds__(256, 2) void k_partials(const float* __restrict__ pred,
                                                     const float* __restrict__ tch,
                                                     float* __restrict__ accum) {
  const int tid = threadIdx.x;
  // XCD swizzle: dispatch-linear id n -> (image, ytile) such that adjacent
  // ytiles of one image share an XCD (n%8) and dispatch ~concurrently, turning
  // the 6/14 halo-row re-reads into same-XCD L2 hits. Bijective per image.
  const int n     = blockIdx.y * gridDim.x + blockIdx.x;
  const int b     = n >> 7;                              // image (gridDim.x == 128)
  const int ytile = (n & 7) * 16 + ((n >> 3) & 15);      // 0..127
  const int y0    = ytile * TH;
  const int x0    = tid * 4;
  const float* tb = tch  + (size_t)b * (H_ * W_);
  const float* pb = pred + (size_t)b * (H_ * W_);

  float acc[NACC];
#pragma unroll
  for (int j = 0; j < NACC; j++) acc[j] = 0.f;

  // register ring queues (indices constant-fold after full unroll)
  float h0q[7][4];
  float h3M[5][4], h3N[5][4];
  float h5M[6][4], h5N[6][4];
  float h7M[4][4], h7N[4][4];

#pragma unroll
  for (int s = 0; s < STEPS; ++s) {
    const int t    = y0 + s - 3;
    const int trow = t < 0 ? 0 : (t >= H_ ? H_ - 1 : t);   // exact (subset argument)
    const float* tr = tb + (size_t)trow * W_;

    // a[0..11] = columns x0-4 .. x0+7, x-clamped at image edges (exact).
    float a[12];
    const float4 cv = *reinterpret_cast<const float4*>(tr + x0);
    a[4] = cv.x; a[5] = cv.y; a[6] = cv.z; a[7] = cv.w;
    if (tid > 0) {
      const float4 lv = *reinterpret_cast<const float4*>(tr + x0 - 4);
      a[0] = lv.x; a[1] = lv.y; a[2] = lv.z; a[3] = lv.w;
    } else {
      a[0] = a[1] = a[2] = a[3] = cv.x;
    }
    if (tid < 255) {
      const float4 rv = *reinterpret_cast<const float4*>(tr + x0 + 4);
      a[8] = rv.x; a[9] = rv.y; a[10] = rv.z; a[11] = rv.w;
    } else {
      a[8] = a[9] = a[10] = a[11] = cv.w;
    }

    // 3-wide sliding windows Q[i] over a[i..i+2] (v_max3 / v_min3)
    float QM[8], QN[8];
#pragma unroll
    for (int i = 1; i <= 7; ++i) {
      QM[i] = fmaxf(fmaxf(a[i], a[i + 1]), a[i + 2]);
      QN[i] = fminf(fminf(a[i], a[i + 1]), a[i + 2]);
    }
    // push this row's windows
#pragma unroll
    for (int c = 0; c < 4; ++c) {
      h0q[s % 7][c] = a[c + 4];
      h3M[s % 5][c] = QM[c + 3];
      h3N[s % 5][c] = QN[c + 3];
      h5M[s % 6][c] = fmaxf(QM[c + 2], QM[c + 4]);
      h5N[s % 6][c] = fminf(QN[c + 2], QN[c + 4]);
      h7M[s % 4][c] = fmaxf(fmaxf(QM[c + 1], QM[c + 4]), a[c + 7]);
      h7N[s % 4][c] = fminf(fminf(QN[c + 1], QN[c + 4]), a[c + 7]);
    }

    // emit output row y = t-3  (row y+d was pushed at step s-3+d)
    if (s >= 6) {
      const int j = s - 6;
      const float4 pv = *reinterpret_cast<const float4*>(pb + (size_t)(y0 + j) * W_ + x0);
      const float p[4] = {pv.x, pv.y, pv.z, pv.w};
#pragma unroll
      for (int c = 0; c < 4; ++c) {
        const float d3v = fmaxf(fmaxf(h3M[(s + 2) % 5][c], h0q[(s + 3) % 7][c]), h0q[(s + 5) % 7][c]);
        const float e3v = fminf(fminf(h3N[(s + 2) % 5][c], h0q[(s + 3) % 7][c]), h0q[(s + 5) % 7][c]);

        float d5v = fmaxf(fmaxf(h5M[(s + 3) % 6][c], h3M[(s + 1) % 5][c]), h3M[(s + 3) % 5][c]);
        d5v = fmaxf(fmaxf(d5v, h0q[(s + 2) % 7][c]), h0q[(s + 6) % 7][c]);
        float e5v = fminf(fminf(h5N[(s + 3) % 6][c], h3N[(s + 1) % 5][c]), h3N[(s + 3) % 5][c]);
        e5v = fminf(fminf(e5v, h0q[(s + 2) % 7][c]), h0q[(s + 6) % 7][c]);

        float d7v = fmaxf(fmaxf(h7M[(s + 1) % 4][c], h5M[(s + 2) % 6][c]), h5M[(s + 4) % 6][c]);
        d7v = fmaxf(fmaxf(d7v, h5M[(s + 1) % 6][c]), h5M[(s + 5) % 6][c]);
        d7v = fmaxf(fmaxf(d7v, h0q[(s + 1) % 7][c]), h0q[s % 7][c]);
        float e7v = fminf(fminf(h7N[(s + 1) % 4][c], h5N[(s + 2) % 6][c]), h5N[(s + 4) % 6][c]);
        e7v = fminf(fminf(e7v, h5N[(s + 1) % 6][c]), h5N[(s + 5) % 6][c]);
        e7v = fminf(fminf(e7v, h0q[(s + 1) % 7][c]), h0q[s % 7][c]);

        acc[0]  += p[c];
        acc[1]  += d3v;  acc[2]  = fmaf(p[c], d3v, acc[2]);
        acc[3]  += e3v;  acc[4]  = fmaf(p[c], e3v, acc[4]);
        acc[5]  += d5v;  acc[6]  = fmaf(p[c], d5v, acc[6]);
        acc[7]  += e5v;  acc[8]  = fmaf(p[c], e5v, acc[8]);
        acc[9]  += d7v;  acc[10] = fmaf(p[c], d7v, acc[10]);
        acc[11] += e7v;  acc[12] = fmaf(p[c], e7v, acc[12]);
      }
    }
  }

  // wave (64-lane) shuffle reduction, then cross-wave via LDS
#pragma unroll
  for (int j = 0; j < NACC; j++) {
    float v = acc[j];
#pragma unroll
    for (int off = 32; off > 0; off >>= 1) v += __shfl_down(v, off, 64);
    acc[j] = v;
  }
  __shared__ float red[4][NACC];
  const int lane = tid & 63, wv = tid >> 6;
  if (lane == 0) {
#pragma unroll
    for (int j = 0; j < NACC; j++) red[wv][j] = acc[j];
  }
  __syncthreads();
  // 13 lanes issue one atomicAdd each; counters are 64B apart -> 13 parallel
  // TCC lines, ~2048 adds per line. fp32 atomic rounding ~1e-5 rel: harmless.
  if (tid < NACC)
    atomicAdd(&accum[tid * ACC_STRIDE],
              red[0][tid] + red[1][tid] + red[2][tid] + red[3][tid]);
}

__global__ void k_final(const float* __restrict__ accum, float* __restrict__ out) {
  const int lane = threadIdx.x;
  const float v = (lane < NACC) ? accum[lane * ACC_STRIDE] : 0.f;
  double t_[NACC];
#pragma unroll
  for (int j = 0; j < NACC; j++) t_[j] = (double)__shfl(v, j, 64);
  if (lane == 0) {
    const double Sp = t_[0];
    double total = 0.0;
#pragma unroll
    for (int k = 0; k < 3; k++) {
      const double Sd = t_[1 + 4 * k], Id = t_[2 + 4 * k];
      const double Se = t_[3 + 4 * k], Ie = t_[4 + 4 * k];
      double cd = Sp + Sd; if (cd < 1e-7) cd = 1e-7;
      double ce = Sp + Se; if (ce < 1e-7) ce = 1e-7;
      total += (1.0 - 2.0 * Id / cd) * (Sd > 0.0 ? 1.0 : 0.0);
      total += (1.0 - 2.0 * Ie / ce) * (Se > 0.0 ? 1.0 : 0.0);
    }
    out[0] = (float)(total / 3.0);
  }
}

extern "C" void kernel_launch(void* const* d_in, const int* in_sizes, int n_in,
                              void* d_out, int out_size, void* d_ws, size_t ws_size,
                              hipStream_t stream) {
  const float* pred = (const float*)d_in[0];  // pred_student_prob
  const float* tch  = (const float*)d_in[1];  // teacher_prob
  float* accum = (float*)d_ws;                // NACC*ACC_STRIDE floats

  hipMemsetAsync(accum, 0, NACC * ACC_STRIDE * sizeof(float), stream);  // capture-safe
  k_partials<<<dim3(GX, B_), 256, 0, stream>>>(pred, tch, accum);
  k_final<<<1, 64, 0, stream>>>(accum, (float*)d_out);
}

// Round 7
// 147.690 us; speedup vs baseline: 1.5750x; 1.2145x over previous
//
#include <hip/hip_runtime.h>

// Problem constants (B, C=1, H, W) from the reference.
#define H_ 1024
#define W_ 1024
#define B_ 16
#define TH 8                   // output rows per block (STEPS=14 fully unrolls; 22 spilled - r3)
#define STEPS (TH + 6)         // input rows streamed (halo 3 each side)
#define GX (H_ / TH)           // 128 y-tiles per image
#define NBLK (GX * B_)         // 2048 blocks
#define NACC 13
#define TROW 1032              // LDS row pitch in floats: 4 pad | 1024 cols | 4 pad

// partials layout (SoA): partials[j * NBLK + bid]
//  j: 0=sum_pred, then k=3,5,7: {1,5,9}=sum_dil {2,6,10}=sum_p*dil
//                               {3,7,11}=sum_ero {4,8,12}=sum_p*ero

// async global->LDS, 16B per lane; lds dest wave-uniform base (+lane*16 implicit)
__device__ __forceinline__ void gl2lds16(const float* g, float* l) {
  __builtin_amdgcn_global_load_lds(
      (const __attribute__((address_space(1))) void*)g,
      (__attribute__((address_space(3))) void*)l,
      16, 0, 0);
}

// Bulk-staged joint dilation+erosion stencil.
// Phase 1: fire ALL 14 teacher-row stages (global_load_lds) + all 8 pred
//          float4 loads -> ~88KB in flight per block, HBM-BW-limited staging.
// Phase 2: ONE __syncthreads (vmcnt drain), then r2's verified ring-queue
//          compute fed by ds_read_b128.
// Algebra (verified r2): h0/h3/h5/h7 per row, output row y = t-3:
//   k3 = op(h3[y], h0[y+/-1]); k5 = op(h5[y], h3[y+/-1], h0[y+/-2]);
//   k7 = op(h7[y], h5[y+/-1], h5[y+/-2], h0[y+/-3])
// Geodesic border == clamped-index border (clamped taps duplicate values in a
// superset window part) -> exact.
__global__ __launch_bounds__(256) void k_partials(const float* __restrict__ pred,
                                                  const float* __restrict__ tch,
                                                  float* __restrict__ partials) {
  __shared__ float tbuf[STEPS][TROW];   // 14 x 1032 x 4B = 57.8KB -> 2 blocks/CU
  __shared__ float red[4][NACC];

  const int tid = threadIdx.x;
  // XCD swizzle (r6, FETCH 90->67MB): consecutive same-XCD blocks (n%8 fixed)
  // get consecutive y-tiles -> halo stages hit that XCD's L2/L3.
  const int n     = blockIdx.y * gridDim.x + blockIdx.x;
  const int b     = n >> 7;                              // image (gridDim.x == 128)
  const int ytile = (n & 7) * 16 + ((n >> 3) & 15);      // bijective 0..127
  const int y0    = ytile * TH;
  const int x0    = tid * 4;
  const int wv    = tid >> 6;
  const float* tb = tch  + (size_t)b * (H_ * W_);
  const float* pb = pred + (size_t)b * (H_ * W_);

  // ---- Phase 1: bulk issue. 14 row stages (1KB per wave-instr) ...
#pragma unroll
  for (int s = 0; s < STEPS; ++s) {
    const int t    = y0 + s - 3;
    const int trow = t < 0 ? 0 : (t >= H_ ? H_ - 1 : t);   // y-clamp (exact)
    gl2lds16(tb + (size_t)trow * W_ + x0, &tbuf[s][4 + (wv << 8)]);
  }
  // ... + all 8 pred rows into registers (independent, complete during drain)
  float4 pv[TH];
#pragma unroll
  for (int j = 0; j < TH; ++j)
    pv[j] = *reinterpret_cast<const float4*>(pb + (size_t)(y0 + j) * W_ + x0);

  __syncthreads();   // single vmcnt(0) drain + barrier: everything lands at once

  // ---- Phase 2: compute from LDS (r2 body; ds_read_b128 replaces global loads)
  float acc[NACC];
#pragma unroll
  for (int j = 0; j < NACC; j++) acc[j] = 0.f;

  float h0q[7][4];
  float h3M[5][4], h3N[5][4];
  float h5M[6][4], h5N[6][4];
  float h7M[4][4], h7N[4][4];

#pragma unroll
  for (int s = 0; s < STEPS; ++s) {
    // a[0..11] = cols x0-4 .. x0+7 (3x ds_read_b128; 16B-aligned)
    const float4* t4 = reinterpret_cast<const float4*>(&tbuf[s][x0]);
    const float4 A0 = t4[0], A1 = t4[1], A2 = t4[2];
    float a[12] = {A0.x, A0.y, A0.z, A0.w, A1.x, A1.y, A1.z, A1.w, A2.x, A2.y, A2.z, A2.w};
    if (tid == 0)   { a[0] = a[1] = a[2]  = a[3]  = a[4]; }   // x-clamp (exact, r5-verified)
    if (tid == 255) { a[8] = a[9] = a[10] = a[11] = a[7]; }

    float QM[8], QN[8];
#pragma unroll
    for (int i = 1; i <= 7; ++i) {
      QM[i] = fmaxf(fmaxf(a[i], a[i + 1]), a[i + 2]);   // v_max3
      QN[i] = fminf(fminf(a[i], a[i + 1]), a[i + 2]);   // v_min3
    }
#pragma unroll
    for (int c = 0; c < 4; ++c) {
      h0q[s % 7][c] = a[c + 4];
      h3M[s % 5][c] = QM[c + 3];
      h3N[s % 5][c] = QN[c + 3];
      h5M[s % 6][c] = fmaxf(QM[c + 2], QM[c + 4]);
      h5N[s % 6][c] = fminf(QN[c + 2], QN[c + 4]);
      h7M[s % 4][c] = fmaxf(fmaxf(QM[c + 1], QM[c + 4]), a[c + 7]);
      h7N[s % 4][c] = fminf(fminf(QN[c + 1], QN[c + 4]), a[c + 7]);
    }

    if (s >= 6) {
      const float4 pq = pv[s - 6];
      const float p[4] = {pq.x, pq.y, pq.z, pq.w};
#pragma unroll
      for (int c = 0; c < 4; ++c) {
        const float d3v = fmaxf(fmaxf(h3M[(s + 2) % 5][c], h0q[(s + 3) % 7][c]), h0q[(s + 5) % 7][c]);
        const float e3v = fminf(fminf(h3N[(s + 2) % 5][c], h0q[(s + 3) % 7][c]), h0q[(s + 5) % 7][c]);

        float d5v = fmaxf(fmaxf(h5M[(s + 3) % 6][c], h3M[(s + 1) % 5][c]), h3M[(s + 3) % 5][c]);
        d5v = fmaxf(fmaxf(d5v, h0q[(s + 2) % 7][c]), h0q[(s + 6) % 7][c]);
        float e5v = fminf(fminf(h5N[(s + 3) % 6][c], h3N[(s + 1) % 5][c]), h3N[(s + 3) % 5][c]);
        e5v = fminf(fminf(e5v, h0q[(s + 2) % 7][c]), h0q[(s + 6) % 7][c]);

        float d7v = fmaxf(fmaxf(h7M[(s + 1) % 4][c], h5M[(s + 2) % 6][c]), h5M[(s + 4) % 6][c]);
        d7v = fmaxf(fmaxf(d7v, h5M[(s + 1) % 6][c]), h5M[(s + 5) % 6][c]);
        d7v = fmaxf(fmaxf(d7v, h0q[(s + 1) % 7][c]), h0q[s % 7][c]);
        float e7v = fminf(fminf(h7N[(s + 1) % 4][c], h5N[(s + 2) % 6][c]), h5N[(s + 4) % 6][c]);
        e7v = fminf(fminf(e7v, h5N[(s + 1) % 6][c]), h5N[(s + 5) % 6][c]);
        e7v = fminf(fminf(e7v, h0q[(s + 1) % 7][c]), h0q[s % 7][c]);

        acc[0]  += p[c];
        acc[1]  += d3v;  acc[2]  = fmaf(p[c], d3v, acc[2]);
        acc[3]  += e3v;  acc[4]  = fmaf(p[c], e3v, acc[4]);
        acc[5]  += d5v;  acc[6]  = fmaf(p[c], d5v, acc[6]);
        acc[7]  += e5v;  acc[8]  = fmaf(p[c], e5v, acc[8]);
        acc[9]  += d7v;  acc[10] = fmaf(p[c], d7v, acc[10]);
        acc[11] += e7v;  acc[12] = fmaf(p[c], e7v, acc[12]);
      }
    }
  }

  // wave (64-lane) shuffle reduction, then cross-wave via LDS
#pragma unroll
  for (int j = 0; j < NACC; j++) {
    float v = acc[j];
#pragma unroll
    for (int off = 32; off > 0; off >>= 1) v += __shfl_down(v, off, 64);
    acc[j] = v;
  }
  const int lane = tid & 63;
  if (lane == 0) {
#pragma unroll
    for (int j = 0; j < NACC; j++) red[wv][j] = acc[j];
  }
  __syncthreads();
  if (tid == 0) {
    const int bid = n;   // any bijective block id
#pragma unroll
    for (int j = 0; j < NACC; j++)
      partials[j * NBLK + bid] = red[0][j] + red[1][j] + red[2][j] + red[3][j];
  }
}

__global__ __launch_bounds__(256) void k_final(const float* __restrict__ partials,
                                               float* __restrict__ out) {
  const int tid = threadIdx.x;
  double acc[NACC];
#pragma unroll
  for (int j = 0; j < NACC; j++) acc[j] = 0.0;
#pragma unroll
  for (int k = 0; k < NBLK / 256; k++) {
#pragma unroll
    for (int j = 0; j < NACC; j++)
      acc[j] += (double)partials[j * NBLK + tid + k * 256];   // coalesced, independent
  }
#pragma unroll
  for (int j = 0; j < NACC; j++) {
#pragma unroll
    for (int off = 32; off > 0; off >>= 1) acc[j] += __shfl_down(acc[j], off, 64);
  }
  __shared__ double red[4][NACC];
  const int lane = tid & 63, wv = tid >> 6;
  if (lane == 0) {
#pragma unroll
    for (int j = 0; j < NACC; j++) red[wv][j] = acc[j];
  }
  __syncthreads();
  if (tid == 0) {
    double t_[NACC];
#pragma unroll
    for (int j = 0; j < NACC; j++) t_[j] = red[0][j] + red[1][j] + red[2][j] + red[3][j];
    const double Sp = t_[0];
    double total = 0.0;
#pragma unroll
    for (int k = 0; k < 3; k++) {
      const double Sd = t_[1 + 4 * k], Id = t_[2 + 4 * k];
      const double Se = t_[3 + 4 * k], Ie = t_[4 + 4 * k];
      double cd = Sp + Sd; if (cd < 1e-7) cd = 1e-7;
      double ce = Sp + Se; if (ce < 1e-7) ce = 1e-7;
      total += (1.0 - 2.0 * Id / cd) * (Sd > 0.0 ? 1.0 : 0.0);
      total += (1.0 - 2.0 * Ie / ce) * (Se > 0.0 ? 1.0 : 0.0);
    }
    out[0] = (float)(total / 3.0);
  }
}

extern "C" void kernel_launch(void* const* d_in, const int* in_sizes, int n_in,
                              void* d_out, int out_size, void* d_ws, size_t ws_size,
                              hipStream_t stream) {
  const float* pred = (const float*)d_in[0];  // pred_student_prob
  const float* tch  = (const float*)d_in[1];  // teacher_prob
  float* partials = (float*)d_ws;             // NACC * NBLK floats; fully written each launch

  k_partials<<<dim3(GX, B_), 256, 0, stream>>>(pred, tch, partials);
  k_final<<<1, 256, 0, stream>>>(partials, (float*)d_out);
}